// Round 6
// baseline (296.562 us; speedup 1.0000x reference)
//
#include <hip/hip_runtime.h>

#define WT_L0 8192
#define WT_NT 512

typedef float f4 __attribute__((ext_vector_type(4)));

// Fully-register pipeline: each thread owns x[16t..16t+16) of one row and
// produces all three output scales for that span. No LDS, no barriers.
__global__ __launch_bounds__(WT_NT) void wavelet1d_kernel(
    const float* __restrict__ x,
    const float* __restrict__ w0,
    const float* __restrict__ w1,
    const float* __restrict__ w2,
    float* __restrict__ out)
{
    const int row = blockIdx.x;
    const int t   = threadIdx.x;                  // 0..511
    const float* __restrict__ xr = x + (size_t)row * WT_L0;
    float* __restrict__ outr = out + (size_t)row * 3 * WT_L0;

    float f0[3], f1[5], f2a[7];
    #pragma unroll
    for (int k = 0; k < 3; ++k) f0[k] = w0[k];
    #pragma unroll
    for (int k = 0; k < 5; ++k) f1[k] = w1[k];
    #pragma unroll
    for (int k = 0; k < 7; ++k) f2a[k] = w2[k];

    // composed pool∘conv5 (stride-2, 6 taps), pool∘conv7 (stride-2, 8 taps)
    const float g0 = 0.5f*f1[0], g1 = 0.5f*(f1[0]+f1[1]), g2 = 0.5f*(f1[1]+f1[2]),
                g3 = 0.5f*(f1[2]+f1[3]), g4 = 0.5f*(f1[3]+f1[4]), g5 = 0.5f*f1[4];
    const float h0 = 0.5f*f2a[0], h1 = 0.5f*(f2a[0]+f2a[1]), h2 = 0.5f*(f2a[1]+f2a[2]),
                h3 = 0.5f*(f2a[2]+f2a[3]), h4 = 0.5f*(f2a[3]+f2a[4]),
                h5 = 0.5f*(f2a[4]+f2a[5]), h6 = 0.5f*(f2a[5]+f2a[6]), h7 = 0.5f*f2a[6];

    // ---- load window xa = x[16t-24 .. 16t+36), zero-filled OOB ----
    float xa[60];
    {
        const f4* __restrict__ xr4 = (const f4*)xr;
        const int qbase = 4 * t - 6;
        if (t >= 2 && t <= 509) {                 // interior: unguarded loads
            #pragma unroll
            for (int c = 0; c < 15; ++c) {
                f4 v = xr4[qbase + c];
                xa[4*c+0] = v.x; xa[4*c+1] = v.y; xa[4*c+2] = v.z; xa[4*c+3] = v.w;
            }
        } else {
            #pragma unroll
            for (int c = 0; c < 15; ++c) {
                int q = qbase + c;
                f4 v = (q >= 0 && q < 2048) ? xr4[q] : (f4)(0.f);
                xa[4*c+0] = v.x; xa[4*c+1] = v.y; xa[4*c+2] = v.z; xa[4*c+3] = v.w;
            }
        }
    }

    // ---- out0 = conv3(x) : out0[16t+e] = f0·x[16t+e-1..+1], x[g]=xa[g-16t+24] ----
    {
        f4* __restrict__ out0_4 = (f4*)outr;
        #pragma unroll
        for (int c = 0; c < 4; ++c) {
            f4 o;
            o.x = f0[0]*xa[4*c+23] + f0[1]*xa[4*c+24] + f0[2]*xa[4*c+25];
            o.y = f0[0]*xa[4*c+24] + f0[1]*xa[4*c+25] + f0[2]*xa[4*c+26];
            o.z = f0[0]*xa[4*c+25] + f0[1]*xa[4*c+26] + f0[2]*xa[4*c+27];
            o.w = f0[0]*xa[4*c+26] + f0[1]*xa[4*c+27] + f0[2]*xa[4*c+28];
            __builtin_nontemporal_store(o, &out0_4[4*t + c]);
        }
    }

    // ---- s1[a] = sig1[8t-10+a] = pool(x), a=0..27 ----
    float s1[28];
    #pragma unroll
    for (int a = 0; a < 28; ++a) s1[a] = 0.5f * (xa[2*a+4] + xa[2*a+5]);

    // ---- s2[b] = sig2[4t-5+b] = pool(sig1), b=0..13 ----
    float s2[14];
    #pragma unroll
    for (int b = 0; b < 14; ++b) s2[b] = 0.5f * (s1[2*b] + s1[2*b+1]);

    // ---- d1[mm] = down1[4t-1+mm] = (pool∘conv5)(sig1), mm=0..5 ----
    // down1[m] = Σ_{i=0..5} g_i·sig1[2m-2+i]; local: s1[6+2mm+i]
    float d1[6];
    #pragma unroll
    for (int mm = 0; mm < 6; ++mm)
        d1[mm] = g0*s1[6+2*mm] + g1*s1[7+2*mm] + g2*s1[8+2*mm]
               + g3*s1[9+2*mm] + g4*s1[10+2*mm] + g5*s1[11+2*mm];

    // ---- d2[nn] = down2[2t-1+nn] = (pool∘conv7)(sig2), nn=0..3 ----
    // down2[m] = Σ_{i=0..7} h_i·sig2[2m-3+i]; local: s2[2nn+i]
    float d2[4];
    #pragma unroll
    for (int nn = 0; nn < 4; ++nn)
        d2[nn] = h0*s2[2*nn+0] + h1*s2[2*nn+1] + h2*s2[2*nn+2] + h3*s2[2*nn+3]
               + h4*s2[2*nn+4] + h5*s2[2*nn+5] + h6*s2[2*nn+6] + h7*s2[2*nn+7];

    // ---- out1 = up2(up2(down1)): out1[4q..4q+4) from down1[q-1,q,q+1] ----
    {
        f4* __restrict__ out1_4 = (f4*)(outr + WT_L0);
        #pragma unroll
        for (int c = 0; c < 4; ++c) {
            int q = 4*t + c;                     // global down1 index
            float d0 = d1[c+1];
            float dm = (q > 0)    ? d1[c]   : d0;   // interp edge-replicate
            float dp = (q < 2047) ? d1[c+2] : d0;
            f4 o;
            o.x = 0.375f  * dm + 0.625f * d0;
            o.y = 0.1875f * dm + 0.75f  * d0 + 0.0625f * dp;
            o.z = 0.0625f * dm + 0.75f  * d0 + 0.1875f * dp;
            o.w = 0.625f  * d0 + 0.375f * dp;
            __builtin_nontemporal_store(o, &out1_4[q]);
        }
    }

    // ---- out2 = (up4∘up2)(down2): out2 f4 q uses down2[m-1,m,m+1], m=q>>1 ----
    {
        f4* __restrict__ out2_4 = (f4*)(outr + 2 * WT_L0);
        #pragma unroll
        for (int c = 0; c < 4; ++c) {
            int q  = 4*t + c;                    // out2 f4 index
            int m  = q >> 1;                     // global down2 index
            int ml = (c >> 1) + 1;               // local (compile-time)
            float d0 = d2[ml];
            float dm = (m > 0)    ? d2[ml-1] : d0;
            float dp = (m < 1023) ? d2[ml+1] : d0;
            f4 wa, wb, wc;
            if ((c & 1) == 0) {
                wa = (f4){0.4375f,  0.3125f,  0.21875f, 0.15625f};
                wb = (f4){0.5625f,  0.6875f,  0.75f,    0.75f   };
                wc = (f4){0.f,      0.f,      0.03125f, 0.09375f};
            } else {
                wa = (f4){0.09375f, 0.03125f, 0.f,      0.f     };
                wb = (f4){0.75f,    0.75f,    0.6875f,  0.5625f };
                wc = (f4){0.15625f, 0.21875f, 0.3125f,  0.4375f };
            }
            f4 o = wa * dm + wb * d0 + wc * dp;
            __builtin_nontemporal_store(o, &out2_4[q]);
        }
    }
}

extern "C" void kernel_launch(void* const* d_in, const int* in_sizes, int n_in,
                              void* d_out, int out_size, void* d_ws, size_t ws_size,
                              hipStream_t stream) {
    const float* x  = (const float*)d_in[0];
    const float* w0 = (const float*)d_in[1];
    const float* w1 = (const float*)d_in[2];
    const float* w2 = (const float*)d_in[3];
    float* out = (float*)d_out;

    const int rows = in_sizes[0] / WT_L0;     // B*C = 2048
    wavelet1d_kernel<<<dim3(rows), dim3(WT_NT), 0, stream>>>(x, w0, w1, w2, out);
}

// Round 7
// 51.203 us; speedup vs baseline: 5.7919x; 5.7919x over previous
//
#include <hip/hip_runtime.h>

#define WT_L0 8192
#define WT_NT 256

typedef float f4 __attribute__((ext_vector_type(4)));
typedef float f2 __attribute__((ext_vector_type(2)));

// Each block does one HALF-row (4096 x-elements) with halo via sig1 staging.
// LDS floats (16.6 KB total):
//   sig1  [0,2072)     f2-cell j holds sig1 global pair g = 1024h-6+j   (0 when OOB)
//   down1 [2080,3108)  ld: gd = 1024h-2+ld
//   sig2  [3108,4144)  ls2: gs2 = 1024h-6+ls2
//   down2 [0,516)      (reuses sig1 region after it dies) ld2: gd2 = 512h-1+ld2
__global__ __launch_bounds__(WT_NT) void wavelet1d_kernel(
    const float* __restrict__ x,
    const float* __restrict__ w0,
    const float* __restrict__ w1,
    const float* __restrict__ w2,
    float* __restrict__ out)
{
    __shared__ float buf[4144];
    const int blk = blockIdx.x;
    const int row = blk >> 1;
    const int h   = blk & 1;
    const int t   = threadIdx.x;
    const float* __restrict__ xr = x + (size_t)row * WT_L0;
    float* __restrict__ outr = out + (size_t)row * 3 * WT_L0;

    float f0[3], f1[5], f2a[7];
    #pragma unroll
    for (int k = 0; k < 3; ++k) f0[k] = w0[k];
    #pragma unroll
    for (int k = 0; k < 5; ++k) f1[k] = w1[k];
    #pragma unroll
    for (int k = 0; k < 7; ++k) f2a[k] = w2[k];

    // composed pool∘conv5 (stride-2, 6 taps) and pool∘conv7 (stride-2, 8 taps)
    const float g0 = 0.5f*f1[0], g1 = 0.5f*(f1[0]+f1[1]), g2 = 0.5f*(f1[1]+f1[2]),
                g3 = 0.5f*(f1[2]+f1[3]), g4 = 0.5f*(f1[3]+f1[4]), g5 = 0.5f*f1[4];
    const float h0 = 0.5f*f2a[0], h1 = 0.5f*(f2a[0]+f2a[1]), h2 = 0.5f*(f2a[1]+f2a[2]),
                h3 = 0.5f*(f2a[2]+f2a[3]), h4 = 0.5f*(f2a[3]+f2a[4]),
                h5 = 0.5f*(f2a[4]+f2a[5]), h6 = 0.5f*(f2a[5]+f2a[6]), h7 = 0.5f*f2a[6];

    float* sig1  = buf;            // f2 cells [0,1036)
    float* down1 = buf + 2080;     // [0,1028)
    float* sig2  = buf + 3108;     // [0,1036)

    // ---- P1: stage sig1 (with halo, OOB=0) + conv3 -> out0 for own span ----
    {
        const f4* __restrict__ xr4 = (const f4*)xr;
        f4* __restrict__ out0_4 = (f4*)outr;
        f2* sig1_2 = (f2*)sig1;
        const int Gbase = 1024 * h - 6;
        for (int j = t; j < 1036; j += WT_NT) {
            const int G = Gbase + j;                 // global x f4 index
            f4 v = (G >= 0 && G < 2048) ? xr4[G] : (f4)(0.f);
            f2 s; s.x = 0.5f * (v.x + v.y); s.y = 0.5f * (v.z + v.w);
            sig1_2[j] = s;
            if (j >= 6 && j < 1030) {                // own span: G in [1024h, 1024h+1024)
                float lm = (G > 0)    ? xr[4 * G - 1] : 0.f;
                float rp = (G < 2047) ? xr[4 * G + 4] : 0.f;
                f4 o;
                o.x = f0[0]*lm  + f0[1]*v.x + f0[2]*v.y;
                o.y = f0[0]*v.x + f0[1]*v.y + f0[2]*v.z;
                o.z = f0[0]*v.y + f0[1]*v.z + f0[2]*v.w;
                o.w = f0[0]*v.z + f0[1]*v.w + f0[2]*rp;
                __builtin_nontemporal_store(o, &out0_4[G]);
            }
        }
    }
    __syncthreads();

    // ---- P2: down1 = (pool∘conv5)(sig1); sig2 = pool(sig1) ----
    {
        const f2* sig1_2 = (const f2*)sig1;
        #pragma unroll
        for (int c = 0; c < 5; ++c) {                // 1028 cells
            int ld = t + WT_NT * c;
            if (ld < 1028) {
                f2 a = sig1_2[ld + 3], b = sig1_2[ld + 4], cc = sig1_2[ld + 5];
                down1[ld] = g0*a.x + g1*a.y + g2*b.x + g3*b.y + g4*cc.x + g5*cc.y;
            }
        }
        #pragma unroll
        for (int c = 0; c < 5; ++c) {                // 1036 cells
            int ls2 = t + WT_NT * c;
            if (ls2 < 1036) {
                f2 p = sig1_2[ls2];
                sig2[ls2] = 0.5f * (p.x + p.y);
            }
        }
    }
    __syncthreads();

    // ---- P3: out1 = up2(up2(down1)); down2 = (pool∘conv7)(sig2) -> buf[0,516) ----
    {
        f4* __restrict__ out1_4 = (f4*)(outr + WT_L0);
        const int qbase = 1024 * h;
        #pragma unroll
        for (int c = 0; c < 4; ++c) {
            int lq = t + WT_NT * c;                  // 0..1023
            int q  = qbase + lq;                     // global down1/out1-f4 index
            int ld = lq + 2;
            float d0 = down1[ld];
            float dm = (q > 0)    ? down1[ld - 1] : d0;
            float dp = (q < 2047) ? down1[ld + 1] : d0;
            f4 o;
            o.x = 0.375f  * dm + 0.625f * d0;
            o.y = 0.1875f * dm + 0.75f  * d0 + 0.0625f * dp;
            o.z = 0.0625f * dm + 0.75f  * d0 + 0.1875f * dp;
            o.w = 0.625f  * d0 + 0.375f * dp;
            __builtin_nontemporal_store(o, &out1_4[q]);
        }
        float* down2 = buf;                          // sig1 dead
        #pragma unroll
        for (int c = 0; c < 3; ++c) {                // 514 cells
            int ld2 = t + WT_NT * c;
            if (ld2 < 514) {
                int b = 2 * ld2 + 1;                 // sig2 local base
                down2[ld2] = h0*sig2[b]   + h1*sig2[b+1] + h2*sig2[b+2] + h3*sig2[b+3]
                           + h4*sig2[b+4] + h5*sig2[b+5] + h6*sig2[b+6] + h7*sig2[b+7];
            }
        }
    }
    __syncthreads();

    const float* down2 = buf;

    // ---- P4: out2 = (up4∘up2)(down2) ----
    {
        f4* __restrict__ out2_4 = (f4*)(outr + 2 * WT_L0);
        const int p = t & 1;                         // parity, constant per thread
        f4 wa, wb, wc;
        if (p == 0) {
            wa = (f4){0.4375f,  0.3125f,  0.21875f, 0.15625f};
            wb = (f4){0.5625f,  0.6875f,  0.75f,    0.75f   };
            wc = (f4){0.f,      0.f,      0.03125f, 0.09375f};
        } else {
            wa = (f4){0.09375f, 0.03125f, 0.f,      0.f     };
            wb = (f4){0.75f,    0.75f,    0.6875f,  0.5625f };
            wc = (f4){0.15625f, 0.21875f, 0.3125f,  0.4375f };
        }
        #pragma unroll
        for (int c = 0; c < 4; ++c) {
            int lq = t + WT_NT * c;                  // 0..1023
            int q  = 1024 * h + lq;                  // global out2 f4 index
            int m  = q >> 1;                         // global down2 index
            int ld2 = (lq >> 1) + 1;
            float d0 = down2[ld2];
            float dm = (m > 0)    ? down2[ld2 - 1] : d0;
            float dp = (m < 1023) ? down2[ld2 + 1] : d0;
            f4 o = wa * dm + wb * d0 + wc * dp;
            __builtin_nontemporal_store(o, &out2_4[q]);
        }
    }
}

extern "C" void kernel_launch(void* const* d_in, const int* in_sizes, int n_in,
                              void* d_out, int out_size, void* d_ws, size_t ws_size,
                              hipStream_t stream) {
    const float* x  = (const float*)d_in[0];
    const float* w0 = (const float*)d_in[1];
    const float* w1 = (const float*)d_in[2];
    const float* w2 = (const float*)d_in[3];
    float* out = (float*)d_out;

    const int rows = in_sizes[0] / WT_L0;     // B*C = 2048
    wavelet1d_kernel<<<dim3(rows * 2), dim3(WT_NT), 0, stream>>>(x, w0, w1, w2, out);
}